// Round 2
// baseline (47753.421 us; speedup 1.0000x reference)
//
#include <hip/hip_runtime.h>
#include <math.h>

#define TT 512
#define BB 256
#define OBS 128
#define ACT 32
#define HID 512
#define KIN 160     // OBS + ACT
#define GATE3 1536  // 3*HID
#define KTOT 672    // KIN + HID

// ---------------- small utility kernels ----------------

__global__ void k_zero_acc(double* acc) {
  if (threadIdx.x == 0) acc[0] = 0.0;
}

// wT[k][c] = (k<KIN) ? w_ih[c][k] : w_hh[c][k-KIN]   -> [KTOT][GATE3]
__global__ void k_transpose_gru(const float* __restrict__ w_ih,
                                const float* __restrict__ w_hh,
                                float* __restrict__ wT) {
  const int n = KTOT * GATE3;
  for (int idx = blockIdx.x * blockDim.x + threadIdx.x; idx < n;
       idx += gridDim.x * blockDim.x) {
    int k = idx / GATE3, c = idx - k * GATE3;
    wT[idx] = (k < KIN) ? w_ih[c * KIN + k] : w_hh[c * HID + (k - KIN)];
  }
}

// wT[k][m] = w[m][k]   (w is [M][K] row-major)
__global__ void k_transpose(const float* __restrict__ w, float* __restrict__ wT,
                            int K, int M) {
  const int n = K * M;
  for (int idx = blockIdx.x * blockDim.x + threadIdx.x; idx < n;
       idx += gridDim.x * blockDim.x) {
    int k = idx / M, m = idx - k * M;
    wT[idx] = w[m * K + k];
  }
}

// ---------------- GRU step ----------------
// h_out[b][j] = GRUCell(x=[obs_t[b], act_t[b]], h=h_prev[b])[j]
// act_t / h_prev may be null (treated as zeros) for the t=0 initial step.
// grid: (16 j-tiles of 32, 16 b-tiles of 16), block 256.
__global__ __launch_bounds__(256) void k_gru_step(
    const float* __restrict__ obs_t,   // [BB][OBS]
    const float* __restrict__ act_t,   // [BB][ACT] or null
    const float* __restrict__ h_prev,  // [BB][HID] or null
    float* __restrict__ h_out,         // [BB][HID]
    const float* __restrict__ wT,      // [KTOT][GATE3]
    const float* __restrict__ b_ih,    // [GATE3]
    const float* __restrict__ b_hh)    // [GATE3]
{
  __shared__ float xs[16][KTOT];
  const int b0 = blockIdx.y * 16;
  const int j0 = blockIdx.x * 32;

  for (int idx = threadIdx.x; idx < 16 * KTOT; idx += 256) {
    int r = idx / KTOT, k = idx - r * KTOT;
    float v;
    if (k < OBS)       v = obs_t[(b0 + r) * OBS + k];
    else if (k < KIN)  v = act_t ? act_t[(b0 + r) * ACT + (k - OBS)] : 0.f;
    else               v = h_prev ? h_prev[(b0 + r) * HID + (k - KIN)] : 0.f;
    xs[r][k] = v;
  }
  __syncthreads();

  const int jl = threadIdx.x & 31;
  const int br = threadIdx.x >> 5;  // 0..7 -> rows br and br+8
  const int j  = j0 + jl;
  const float* w = wT + j;

  // x-part (gi): k in [0, KIN)
  float ir0 = 0.f, iz0 = 0.f, in0 = 0.f, ir1 = 0.f, iz1 = 0.f, in1 = 0.f;
#pragma unroll 4
  for (int k = 0; k < KIN; ++k) {
    float wr = w[k * GATE3];
    float wz = w[k * GATE3 + HID];
    float wn = w[k * GATE3 + 2 * HID];
    float a0 = xs[br][k], a1 = xs[br + 8][k];
    ir0 += a0 * wr; iz0 += a0 * wz; in0 += a0 * wn;
    ir1 += a1 * wr; iz1 += a1 * wz; in1 += a1 * wn;
  }
  // h-part (gh): k in [KIN, KTOT)
  float hr0 = 0.f, hz0 = 0.f, hn0 = 0.f, hr1 = 0.f, hz1 = 0.f, hn1 = 0.f;
#pragma unroll 4
  for (int k = KIN; k < KTOT; ++k) {
    float wr = w[k * GATE3];
    float wz = w[k * GATE3 + HID];
    float wn = w[k * GATE3 + 2 * HID];
    float a0 = xs[br][k], a1 = xs[br + 8][k];
    hr0 += a0 * wr; hz0 += a0 * wz; hn0 += a0 * wn;
    hr1 += a1 * wr; hz1 += a1 * wz; hn1 += a1 * wn;
  }

  const float bir = b_ih[j], biz = b_ih[j + HID], bin = b_ih[j + 2 * HID];
  const float bhr = b_hh[j], bhz = b_hh[j + HID], bhn = b_hh[j + 2 * HID];

  {
    float r = 1.f / (1.f + expf(-(ir0 + bir + hr0 + bhr)));
    float z = 1.f / (1.f + expf(-(iz0 + biz + hz0 + bhz)));
    float n = tanhf(in0 + bin + r * (hn0 + bhn));
    float hv = xs[br][KIN + j];  // h_prev[b][j] (0 when h_prev null)
    h_out[(size_t)(b0 + br) * HID + j] = (1.f - z) * n + z * hv;
  }
  {
    float r = 1.f / (1.f + expf(-(ir1 + bir + hr1 + bhr)));
    float z = 1.f / (1.f + expf(-(iz1 + biz + hz1 + bhz)));
    float n = tanhf(in1 + bin + r * (hn1 + bhn));
    float hv = xs[br + 8][KIN + j];
    h_out[(size_t)(b0 + br + 8) * HID + j] = (1.f - z) * n + z * hv;
  }
}

// ---------------- generic linear layer (fp32 SGEMM) ----------------
// C[N][M] = act( A[N][K] @ BT[K][M] + bias[M] );  act: 0=none, 1=ELU
// tiles: 128(N) x 128(M), BK=16, block 256 threads, 8x8 per thread.
// N multiple of 128; M handled with bounds checks.
__global__ __launch_bounds__(256) void k_linear(
    const float* __restrict__ A, const float* __restrict__ BT,
    const float* __restrict__ bias, float* __restrict__ C,
    int N, int K, int M, int act)
{
  __shared__ float As[16][129];  // [k][m] padded: conflict-free
  __shared__ float Bs[16][132];  // [k][n] padded, rows 16B-aligned for float4
  const int bm = blockIdx.y * 128;
  const int bn = blockIdx.x * 128;
  const int tx = threadIdx.x & 15;   // n-dim
  const int ty = threadIdx.x >> 4;   // m-dim

  float acc[8][8];
#pragma unroll
  for (int i = 0; i < 8; ++i)
#pragma unroll
    for (int j2 = 0; j2 < 8; ++j2) acc[i][j2] = 0.f;

  for (int k0 = 0; k0 < K; k0 += 16) {
    for (int i = threadIdx.x; i < 2048; i += 256) {
      int r = i >> 4, kk = i & 15;
      As[kk][r] = A[(size_t)(bm + r) * K + (k0 + kk)];
    }
    for (int i = threadIdx.x; i < 2048; i += 256) {
      int kk = i >> 7, c = i & 127;
      int col = bn + c;
      Bs[kk][c] = (col < M) ? BT[(size_t)(k0 + kk) * M + col] : 0.f;
    }
    __syncthreads();
#pragma unroll
    for (int kk = 0; kk < 16; ++kk) {
      float a[8], b[8];
#pragma unroll
      for (int i = 0; i < 8; ++i) a[i] = As[kk][ty * 8 + i];
      float4 b01 = *(const float4*)&Bs[kk][tx * 8];
      float4 b23 = *(const float4*)&Bs[kk][tx * 8 + 4];
      b[0] = b01.x; b[1] = b01.y; b[2] = b01.z; b[3] = b01.w;
      b[4] = b23.x; b[5] = b23.y; b[6] = b23.z; b[7] = b23.w;
#pragma unroll
      for (int i = 0; i < 8; ++i)
#pragma unroll
        for (int j2 = 0; j2 < 8; ++j2) acc[i][j2] += a[i] * b[j2];
    }
    __syncthreads();
  }

#pragma unroll
  for (int i = 0; i < 8; ++i) {
    int row = bm + ty * 8 + i;
#pragma unroll
    for (int j2 = 0; j2 < 8; ++j2) {
      int col = bn + tx * 8 + j2;
      if (col < M) {
        float v = acc[i][j2] + bias[col];
        if (act) v = (v > 0.f) ? v : expm1f(v);
        C[(size_t)row * M + col] = v;
      }
    }
  }
}

// ---------------- loss ----------------
__global__ __launch_bounds__(256) void k_loss(
    const float* __restrict__ obs, const float* __restrict__ action,
    const float* __restrict__ p_obs, const float* __restrict__ p_act,
    const float* __restrict__ p_rew, double* __restrict__ acc)
{
  const long long n1 = (long long)TT * BB * OBS;
  const long long n2 = (long long)TT * BB * ACT;
  const long long n  = n1 + n2 + n2;
  const float C = 0.91893853320467274178f;  // 0.5*ln(2*pi)
  double s = 0.0;
  for (long long idx = (long long)blockIdx.x * blockDim.x + threadIdx.x; idx < n;
       idx += (long long)gridDim.x * blockDim.x) {
    float d;
    if (idx < n1) {
      d = obs[idx] - p_obs[idx];
    } else if (idx < n1 + n2) {
      long long i = idx - n1;
      d = action[i] - p_act[i];
    } else {
      long long i = idx - n1 - n2;
      d = action[i] - p_rew[i >> 5];  // broadcast pre_reward over ACT=32
    }
    s += (double)(0.5f * d * d + C);
  }
  __shared__ double red[256];
  red[threadIdx.x] = s;
  __syncthreads();
  for (int off = 128; off > 0; off >>= 1) {
    if ((int)threadIdx.x < off) red[threadIdx.x] += red[threadIdx.x + off];
    __syncthreads();
  }
  if (threadIdx.x == 0) atomicAdd(acc, red[0]);
}

__global__ void k_finalize(const double* __restrict__ acc, float* __restrict__ out) {
  if (threadIdx.x == 0) out[0] = (float)(acc[0] / (double)(TT * BB));
}

// ---------------- launch ----------------

extern "C" void kernel_launch(void* const* d_in, const int* in_sizes, int n_in,
                              void* d_out, int out_size, void* d_ws, size_t ws_size,
                              hipStream_t stream) {
  const float* obs    = (const float*)d_in[0];
  const float* action = (const float*)d_in[1];
  // d_in[2] = reward, unused by the reference loss
  const float* w_ih = (const float*)d_in[3];
  const float* w_hh = (const float*)d_in[4];
  const float* b_ih = (const float*)d_in[5];
  const float* b_hh = (const float*)d_in[6];
  const float* hw[9] = {(const float*)d_in[7],  (const float*)d_in[9],  (const float*)d_in[11],
                        (const float*)d_in[13], (const float*)d_in[15], (const float*)d_in[17],
                        (const float*)d_in[19], (const float*)d_in[21], (const float*)d_in[23]};
  const float* hb[9] = {(const float*)d_in[8],  (const float*)d_in[10], (const float*)d_in[12],
                        (const float*)d_in[14], (const float*)d_in[16], (const float*)d_in[18],
                        (const float*)d_in[20], (const float*)d_in[22], (const float*)d_in[24]};
  const int hM[9] = {512, 512, 128, 512, 512, 32, 512, 512, 1};

  float* out     = (float*)d_out;
  float* pre_obs = out + 1;
  float* pre_act = pre_obs + (size_t)TT * BB * OBS;
  float* pre_rew = pre_act + (size_t)TT * BB * ACT;

  // ---- workspace layout, sized against the ACTUAL ws_size ----
  char* ws = (char*)d_ws;
  double* acc = (double*)ws;                 // 256 B reserved
  size_t off = 256;
  float* wT_gru = (float*)(ws + off); off += (size_t)KTOT * GATE3 * 4;     // 4.1 MB
  float* wT_head[9];
  for (int i = 0; i < 9; ++i) { wT_head[i] = (float*)(ws + off); off += (size_t)512 * hM[i] * 4; }
  const size_t fixed = off;  // ~10.9 MB

  // Chunked streaming over timesteps: hs_chunk + tmp1 + tmp2, each TC*BB*512 floats.
  // Pick largest TC (power of 2, divides TT) fitting ws_size.
  int TC = 64;
  while (TC > 1 && fixed + 3ull * TC * BB * HID * 4ull > ws_size) TC >>= 1;
  const size_t chunk_elems = (size_t)TC * BB * HID;
  float* hs_chunk = (float*)(ws + off); off += chunk_elems * 4;
  float* tmp1     = (float*)(ws + off); off += chunk_elems * 4;
  float* tmp2     = (float*)(ws + off); off += chunk_elems * 4;
  const int CH = TC * BB;          // rows per chunk (multiple of 128: >=256)
  const int NCH = TT / TC;

  k_zero_acc<<<1, 64, 0, stream>>>(acc);
  k_transpose_gru<<<2048, 256, 0, stream>>>(w_ih, w_hh, wT_gru);
  for (int i = 0; i < 9; ++i) {
    int n = 512 * hM[i];
    int blocks = (n + 255) / 256; if (blocks > 1024) blocks = 1024;
    k_transpose<<<blocks, 256, 0, stream>>>(hw[i], wT_head[i], 512, hM[i]);
  }

  // recurrence + heads, streamed chunk by chunk.
  // hs[0] = gru([obs[0],0], 0); hs[t] = gru(x[t-1], hs[t-1])
  for (int c = 0; c < NCH; ++c) {
    for (int s = 0; s < TC; ++s) {
      const int t = c * TC + s;
      const float* o = obs + (size_t)((t == 0) ? 0 : (t - 1)) * BB * OBS;
      const float* a = (t == 0) ? nullptr : action + (size_t)(t - 1) * BB * ACT;
      // h_prev: slot s-1 of this chunk, or last slot of previous chunk (read-before-
      // overwrite is safe: h_prev and h_out are disjoint slots)
      const float* hp = (t == 0) ? nullptr
                      : (s == 0) ? hs_chunk + (size_t)(TC - 1) * BB * HID
                                 : hs_chunk + (size_t)(s - 1) * BB * HID;
      float* ho = hs_chunk + (size_t)s * BB * HID;
      k_gru_step<<<dim3(16, 16), 256, 0, stream>>>(o, a, hp, ho, wT_gru, b_ih, b_hh);
    }
    for (int h = 0; h < 3; ++h) {
      const float* w0T = wT_head[h * 3 + 0];
      const float* w1T = wT_head[h * 3 + 1];
      const float* w2T = wT_head[h * 3 + 2];
      const float* b0 = hb[h * 3 + 0];
      const float* b1 = hb[h * 3 + 1];
      const float* b2 = hb[h * 3 + 2];
      int M2 = hM[h * 3 + 2];
      float* outp = (h == 0) ? pre_obs + (size_t)c * CH * OBS
                  : (h == 1) ? pre_act + (size_t)c * CH * ACT
                             : pre_rew + (size_t)c * CH;
      k_linear<<<dim3(4, CH / 128), 256, 0, stream>>>(hs_chunk, w0T, b0, tmp1, CH, 512, 512, 1);
      k_linear<<<dim3(4, CH / 128), 256, 0, stream>>>(tmp1, w1T, b1, tmp2, CH, 512, 512, 1);
      k_linear<<<dim3((M2 + 127) / 128, CH / 128), 256, 0, stream>>>(tmp2, w2T, b2, outp, CH, 512, M2, 0);
    }
  }

  k_loss<<<2048, 256, 0, stream>>>(obs, action, pre_obs, pre_act, pre_rew, acc);
  k_finalize<<<1, 64, 0, stream>>>(acc, out);
}

// Round 3
// 4853.606 us; speedup vs baseline: 9.8388x; 9.8388x over previous
//
#include <hip/hip_runtime.h>
#include <math.h>

#define TT 512
#define BB 256
#define OBS 128
#define ACT 32
#define HID 512
#define GATE3 1536  // 3*HID

typedef unsigned short u16;
typedef unsigned int u32;
typedef __attribute__((ext_vector_type(8))) short bf16x8;  // 8 bf16 = 4 VGPRs
typedef __attribute__((ext_vector_type(4))) float f32x4;

__device__ __forceinline__ u16 f2bf(float v) {
  u32 u = __float_as_uint(v);
  u = (u + 0x7fff + ((u >> 16) & 1)) >> 16;  // RNE
  return (u16)u;
}

// ---------------- small utility kernels ----------------

__global__ void k_zero_acc(double* acc) {
  if (threadIdx.x == 0) acc[0] = 0.0;
}

// dst bf16 [Mp][Kp] = zero-padded convert of src fp32 [M][K]
__global__ void k_convert_pad(const float* __restrict__ src, u16* __restrict__ dst,
                              int M, int K, int Mp, int Kp) {
  const int n = Mp * Kp;
  for (int idx = blockIdx.x * blockDim.x + threadIdx.x; idx < n;
       idx += gridDim.x * blockDim.x) {
    int m = idx / Kp, k = idx - m * Kp;
    float v = (m < M && k < K) ? src[(size_t)m * K + k] : 0.f;
    dst[idx] = f2bf(v);
  }
}

// bfold[j] = b_ih[j] + (j<1024 ? b_hh[j] : 0)   (b_hh_n stays separate)
__global__ void k_fold_bias(const float* __restrict__ b_ih,
                            const float* __restrict__ b_hh,
                            float* __restrict__ bf) {
  int j = blockIdx.x * blockDim.x + threadIdx.x;
  if (j < GATE3) bf[j] = b_ih[j] + (j < 1024 ? b_hh[j] : 0.f);
}

// Xb [TC*BB][192] bf16: row (s,b): [obs[t-1], action[t-1], 0pad]; t=0: [obs[0], 0, 0]
__global__ void k_pack_x(const float* __restrict__ obs, const float* __restrict__ action,
                         u16* __restrict__ Xb, int cbase, int TC) {
  const int n = TC * BB * 192;
  for (int idx = blockIdx.x * blockDim.x + threadIdx.x; idx < n;
       idx += gridDim.x * blockDim.x) {
    int rr = idx / 192, cc = idx - rr * 192;
    int s = rr / BB, b = rr - s * BB;
    int t = cbase + s;
    float v = 0.f;
    if (t == 0) {
      if (cc < OBS) v = obs[(size_t)b * OBS + cc];
    } else {
      if (cc < OBS)       v = obs[(size_t)(t - 1) * BB * OBS + (size_t)b * OBS + cc];
      else if (cc < 160)  v = action[(size_t)(t - 1) * BB * ACT + (size_t)b * ACT + (cc - 128)];
    }
    Xb[idx] = f2bf(v);
  }
}

// ---------------- MFMA GEMM (heads + gi) ----------------
// C[N][M] = act( A[N][K] @ B[M][K]^T + bias[M] )
// A bf16 [N][K], B bf16 [Mp][K] (rows >= M are zero pad), K multiple of 64.
// N multiple of 128; grid = (Mp/128, N/128); 256 threads = 4 waves (2x2 quadrants).
// LDS tiles 128x64 bf16, 16B-chunk XOR-swizzled (chunk ^= row&7) for conflict-free b128.
__global__ __launch_bounds__(256) void k_mfma_gemm(
    const u16* __restrict__ A, const u16* __restrict__ B,
    const float* __restrict__ bias,
    float* __restrict__ outf,   // fp32 out (or null)
    u16* __restrict__ outb,     // bf16 out (or null)
    int N, int K, int M, int act)
{
  __shared__ u16 As[128 * 64];
  __shared__ u16 Bs[128 * 64];
  const int bn = blockIdx.y * 128;   // A-row / C-row base
  const int bm = blockIdx.x * 128;   // B-row / C-col base
  const int tid = threadIdx.x;
  const int w = tid >> 6, lane = tid & 63;
  const int wr = w >> 1, wc = w & 1;

  f32x4 acc[4][4];
#pragma unroll
  for (int i = 0; i < 4; ++i)
#pragma unroll
    for (int j = 0; j < 4; ++j) acc[i][j] = (f32x4){0.f, 0.f, 0.f, 0.f};

  const int lr8 = lane >> 3;   // row within 8-row group
  const int lc8 = lane & 7;    // stored chunk

  for (int kt = 0; kt < K; kt += 64) {
    __syncthreads();
#pragma unroll
    for (int i = 0; i < 4; ++i) {
      int r0 = (w * 4 + i) * 8;
      int r = r0 + lr8;
      int c = lc8 ^ (r & 7);
      const u16* ga = A + (size_t)(bn + r) * K + kt + c * 8;
      const u16* gb = B + (size_t)(bm + r) * K + kt + c * 8;
      __builtin_amdgcn_global_load_lds((__attribute__((address_space(1))) const u32*)ga,
                                       (__attribute__((address_space(3))) u32*)(As + r0 * 64), 16, 0, 0);
      __builtin_amdgcn_global_load_lds((__attribute__((address_space(1))) const u32*)gb,
                                       (__attribute__((address_space(3))) u32*)(Bs + r0 * 64), 16, 0, 0);
    }
    __syncthreads();  // drains vmcnt before ds_read

    const int m16 = lane & 15, q = lane >> 4;
#pragma unroll
    for (int kk = 0; kk < 2; ++kk) {
      bf16x8 af[4], bfr[4];
#pragma unroll
      for (int i = 0; i < 4; ++i) {
        int ra = wr * 64 + i * 16 + m16;
        af[i] = *(const bf16x8*)&As[ra * 64 + ((kk * 4 + q) ^ (ra & 7)) * 8];
        int rb = wc * 64 + i * 16 + m16;
        bfr[i] = *(const bf16x8*)&Bs[rb * 64 + ((kk * 4 + q) ^ (rb & 7)) * 8];
      }
#pragma unroll
      for (int i = 0; i < 4; ++i)
#pragma unroll
        for (int j = 0; j < 4; ++j)
          acc[i][j] = __builtin_amdgcn_mfma_f32_16x16x32_bf16(af[i], bfr[j], acc[i][j], 0, 0, 0);
    }
  }

  // epilogue: D col = lane&15, row = (lane>>4)*4 + reg  [m89]
  const int m16 = lane & 15, q = lane >> 4;
#pragma unroll
  for (int i = 0; i < 4; ++i) {
#pragma unroll
    for (int j = 0; j < 4; ++j) {
      int col = bm + wc * 64 + j * 16 + m16;
      if (col >= M) continue;
      float bs = bias[col];
#pragma unroll
      for (int p = 0; p < 4; ++p) {
        int row = bn + wr * 64 + i * 16 + q * 4 + p;
        float v = acc[i][j][p] + bs;
        if (act) v = (v > 0.f) ? v : expm1f(v);
        if (outf) outf[(size_t)row * M + col] = v;
        else      outb[(size_t)row * M + col] = f2bf(v);
      }
    }
  }
}

// ---------------- GRU step (MFMA, fused gates) ----------------
// gh = h_prev @ w_hh^T for a 16b x (32j x 3gate) tile; 4 waves split K=512.
// grid (16 j-tiles, 16 b-tiles), 256 threads. LDS: A 16K + B 96K + red 24K = 136K.
__global__ __launch_bounds__(256) void k_gru_step_mfma(
    const u16* __restrict__ hprev_bf,  // [BB][512] bf16 or null (t==0)
    const float* __restrict__ hprev32, // [BB][512] fp32 or null
    const u16* __restrict__ whh_bf,    // [1536][512] bf16
    const float* __restrict__ gi_t,    // [BB][1536] fp32, biases folded (r,z both; n: b_ih only)
    const float* __restrict__ bhh_n,   // [512] = b_hh + 1024
    float* __restrict__ hout32,        // [BB][512]
    u16* __restrict__ hout_bf)         // [BB][512]
{
  __shared__ u16 As[16 * 512];             // h rows, 1KB rows, 64 chunks XOR-swizzled
  __shared__ u16 Bs[96 * 512];             // w cols (rows of w_hh)
  __shared__ float red[4][6][16][16];      // per-wave partial tiles
  const int jt = blockIdx.x;   // 0..15
  const int bt = blockIdx.y;   // 0..15
  const int tid = threadIdx.x, w = tid >> 6, lane = tid & 63;

  // stage A (16 rows x 1KB, one wave-instr per row)
  if (hprev_bf) {
#pragma unroll
    for (int i = 0; i < 4; ++i) {
      int r = w * 4 + i;
      int c = lane ^ (r & 7);
      const u16* g = hprev_bf + (size_t)(bt * 16 + r) * 512 + c * 8;
      __builtin_amdgcn_global_load_lds((__attribute__((address_space(1))) const u32*)g,
                                       (__attribute__((address_space(3))) u32*)(As + r * 512), 16, 0, 0);
    }
  } else {
    for (int idx = tid; idx < 16 * 512; idx += 256) As[idx] = 0;
  }
  // stage B: 96 lds-rows; lds row cr <-> global col (cr>>5)*512 + jt*32 + (cr&31)
  for (int i = 0; i < 24; ++i) {
    int cr = w * 24 + i;
    int gcol = (cr >> 5) * 512 + jt * 32 + (cr & 31);
    int c = lane ^ (cr & 7);
    const u16* g = whh_bf + (size_t)gcol * 512 + c * 8;
    __builtin_amdgcn_global_load_lds((__attribute__((address_space(1))) const u32*)g,
                                     (__attribute__((address_space(3))) u32*)(Bs + cr * 512), 16, 0, 0);
  }
  __syncthreads();

  // compute: wave w covers K range [w*128, w*128+128)
  const int m16 = lane & 15, q = lane >> 4;
  f32x4 acc[6];
#pragma unroll
  for (int ct = 0; ct < 6; ++ct) acc[ct] = (f32x4){0.f, 0.f, 0.f, 0.f};
#pragma unroll
  for (int kl = 0; kl < 4; ++kl) {
    int cb = w * 16 + kl * 4 + q;  // logical 16B chunk
    bf16x8 af = *(const bf16x8*)&As[m16 * 512 + (cb ^ (m16 & 7)) * 8];
#pragma unroll
    for (int ct = 0; ct < 6; ++ct) {
      int rb = ct * 16 + m16;
      bf16x8 bfr = *(const bf16x8*)&Bs[rb * 512 + (cb ^ (rb & 7)) * 8];
      acc[ct] = __builtin_amdgcn_mfma_f32_16x16x32_bf16(af, bfr, acc[ct], 0, 0, 0);
    }
  }
  // partials to LDS
#pragma unroll
  for (int ct = 0; ct < 6; ++ct)
#pragma unroll
    for (int p = 0; p < 4; ++p) red[w][ct][q * 4 + p][m16] = acc[ct][p];
  __syncthreads();

  // reduce 4 waves + gates; 512 outputs (16b x 32j), 2 per thread
#pragma unroll
  for (int rep = 0; rep < 2; ++rep) {
    int o = rep * 256 + tid;
    int b = o >> 5, jj = o & 31;
    int ti = jj >> 4, tc = jj & 15;
    float gr = 0.f, gz = 0.f, gn = 0.f;
#pragma unroll
    for (int ww = 0; ww < 4; ++ww) {
      gr += red[ww][0 + ti][b][tc];
      gz += red[ww][2 + ti][b][tc];
      gn += red[ww][4 + ti][b][tc];
    }
    int j = jt * 32 + jj;
    int gb = bt * 16 + b;
    float gir = gi_t[(size_t)gb * GATE3 + j];
    float giz = gi_t[(size_t)gb * GATE3 + 512 + j];
    float gin = gi_t[(size_t)gb * GATE3 + 1024 + j];
    float r = 1.f / (1.f + expf(-(gir + gr)));
    float z = 1.f / (1.f + expf(-(giz + gz)));
    float n = tanhf(gin + r * (gn + bhh_n[j]));
    float hv = hprev32 ? hprev32[(size_t)gb * 512 + j] : 0.f;
    float h = (1.f - z) * n + z * hv;
    hout32[(size_t)gb * 512 + j] = h;
    hout_bf[(size_t)gb * 512 + j] = f2bf(h);
  }
}

// ---------------- loss ----------------
__global__ __launch_bounds__(256) void k_loss(
    const float* __restrict__ obs, const float* __restrict__ action,
    const float* __restrict__ p_obs, const float* __restrict__ p_act,
    const float* __restrict__ p_rew, double* __restrict__ acc)
{
  const long long n1 = (long long)TT * BB * OBS;
  const long long n2 = (long long)TT * BB * ACT;
  const long long n  = n1 + n2 + n2;
  const float C = 0.91893853320467274178f;  // 0.5*ln(2*pi)
  double s = 0.0;
  for (long long idx = (long long)blockIdx.x * blockDim.x + threadIdx.x; idx < n;
       idx += (long long)gridDim.x * blockDim.x) {
    float d;
    if (idx < n1) {
      d = obs[idx] - p_obs[idx];
    } else if (idx < n1 + n2) {
      long long i = idx - n1;
      d = action[i] - p_act[i];
    } else {
      long long i = idx - n1 - n2;
      d = action[i] - p_rew[i >> 5];  // broadcast pre_reward over ACT=32
    }
    s += (double)(0.5f * d * d + C);
  }
  __shared__ double red[256];
  red[threadIdx.x] = s;
  __syncthreads();
  for (int off = 128; off > 0; off >>= 1) {
    if ((int)threadIdx.x < off) red[threadIdx.x] += red[threadIdx.x + off];
    __syncthreads();
  }
  if (threadIdx.x == 0) atomicAdd(acc, red[0]);
}

__global__ void k_finalize(const double* __restrict__ acc, float* __restrict__ out) {
  if (threadIdx.x == 0) out[0] = (float)(acc[0] / (double)(TT * BB));
}

// ---------------- launch ----------------

extern "C" void kernel_launch(void* const* d_in, const int* in_sizes, int n_in,
                              void* d_out, int out_size, void* d_ws, size_t ws_size,
                              hipStream_t stream) {
  const float* obs    = (const float*)d_in[0];
  const float* action = (const float*)d_in[1];
  const float* w_ih = (const float*)d_in[3];   // [1536][160]
  const float* w_hh = (const float*)d_in[4];   // [1536][512]
  const float* b_ih = (const float*)d_in[5];
  const float* b_hh = (const float*)d_in[6];
  const float* hw[9] = {(const float*)d_in[7],  (const float*)d_in[9],  (const float*)d_in[11],
                        (const float*)d_in[13], (const float*)d_in[15], (const float*)d_in[17],
                        (const float*)d_in[19], (const float*)d_in[21], (const float*)d_in[23]};
  const float* hb[9] = {(const float*)d_in[8],  (const float*)d_in[10], (const float*)d_in[12],
                        (const float*)d_in[14], (const float*)d_in[16], (const float*)d_in[18],
                        (const float*)d_in[20], (const float*)d_in[22], (const float*)d_in[24]};
  const int hM[9]  = {512, 512, 128, 512, 512, 32, 512, 512, 1};
  const int hMp[9] = {512, 512, 128, 512, 512, 128, 512, 512, 128};

  float* out     = (float*)d_out;
  float* pre_obs = out + 1;
  float* pre_act = pre_obs + (size_t)TT * BB * OBS;
  float* pre_rew = pre_act + (size_t)TT * BB * ACT;

  // ---- workspace ----
  char* ws = (char*)d_ws;
  size_t off = 0;
  auto alloc = [&](size_t bytes) { void* p = ws + off; off = (off + bytes + 255) & ~(size_t)255; return p; };
  double* acc   = (double*)alloc(256);
  u16* whh_bf   = (u16*)alloc((size_t)GATE3 * 512 * 2);
  u16* wih_bf   = (u16*)alloc((size_t)GATE3 * 192 * 2);
  u16* headb[9];
  for (int i = 0; i < 9; ++i) headb[i] = (u16*)alloc((size_t)hMp[i] * 512 * 2);
  float* bfold  = (float*)alloc(GATE3 * 4);
  const size_t fixed = off;

  int TC = 64;
  while (TC > 1 &&
         fixed + (size_t)TC * BB * (GATE3 * 4 /*gi*/ + 512 * 4 /*hs32*/ + 512 * 2 /*hsbf*/ +
                                    2 * 512 * 2 /*tmps*/ + 192 * 2 /*Xb*/) + (1u << 20) > ws_size)
    TC >>= 1;
  const int CH = TC * BB;
  float* gi   = (float*)alloc((size_t)CH * GATE3 * 4);
  float* hs32 = (float*)alloc((size_t)CH * 512 * 4);
  u16* hsbf   = (u16*)alloc((size_t)CH * 512 * 2);
  u16* tmp1b  = (u16*)alloc((size_t)CH * 512 * 2);
  u16* tmp2b  = (u16*)alloc((size_t)CH * 512 * 2);
  u16* Xb     = (u16*)alloc((size_t)CH * 192 * 2);

  // ---- setup ----
  k_zero_acc<<<1, 64, 0, stream>>>(acc);
  k_convert_pad<<<1024, 256, 0, stream>>>(w_hh, whh_bf, GATE3, 512, GATE3, 512);
  k_convert_pad<<<1024, 256, 0, stream>>>(w_ih, wih_bf, GATE3, 160, GATE3, 192);
  for (int i = 0; i < 9; ++i)
    k_convert_pad<<<512, 256, 0, stream>>>(hw[i], headb[i], hM[i], 512, hMp[i], 512);
  k_fold_bias<<<6, 256, 0, stream>>>(b_ih, b_hh, bfold);

  const int NCH = TT / TC;
  for (int c = 0; c < NCH; ++c) {
    const int cbase = c * TC;
    // gi for the chunk: [CH][1536] fp32 = Xb @ wih^T + folded biases
    k_pack_x<<<2048, 256, 0, stream>>>(obs, action, Xb, cbase, TC);
    k_mfma_gemm<<<dim3(GATE3 / 128, CH / 128), 256, 0, stream>>>(
        Xb, wih_bf, bfold, gi, nullptr, CH, 192, GATE3, 0);
    // recurrence
    for (int s = 0; s < TC; ++s) {
      const int t = cbase + s;
      const u16* hpb = (t == 0) ? nullptr
                     : (s == 0) ? hsbf + (size_t)(TC - 1) * BB * 512
                                : hsbf + (size_t)(s - 1) * BB * 512;
      const float* hp32 = (t == 0) ? nullptr
                        : (s == 0) ? hs32 + (size_t)(TC - 1) * BB * 512
                                   : hs32 + (size_t)(s - 1) * BB * 512;
      k_gru_step_mfma<<<dim3(16, 16), 256, 0, stream>>>(
          hpb, hp32, whh_bf, gi + (size_t)s * BB * GATE3, b_hh + 1024,
          hs32 + (size_t)s * BB * 512, hsbf + (size_t)s * BB * 512);
    }
    // heads
    for (int h = 0; h < 3; ++h) {
      int M2 = hM[h * 3 + 2], Mp2 = hMp[h * 3 + 2];
      float* outp = (h == 0) ? pre_obs + (size_t)c * CH * OBS
                  : (h == 1) ? pre_act + (size_t)c * CH * ACT
                             : pre_rew + (size_t)c * CH;
      k_mfma_gemm<<<dim3(4, CH / 128), 256, 0, stream>>>(
          hsbf, headb[h * 3 + 0], hb[h * 3 + 0], nullptr, tmp1b, CH, 512, 512, 1);
      k_mfma_gemm<<<dim3(4, CH / 128), 256, 0, stream>>>(
          tmp1b, headb[h * 3 + 1], hb[h * 3 + 1], nullptr, tmp2b, CH, 512, 512, 1);
      k_mfma_gemm<<<dim3(Mp2 / 128, CH / 128), 256, 0, stream>>>(
          tmp2b, headb[h * 3 + 2], hb[h * 3 + 2], outp, nullptr, CH, 512, M2, 0);
    }
  }

  k_loss<<<2048, 256, 0, stream>>>(obs, action, pre_obs, pre_act, pre_rew, acc);
  k_finalize<<<1, 64, 0, stream>>>(acc, out);
}